// Round 18
// baseline (126.437 us; speedup 1.0000x reference)
//
#include <hip/hip_runtime.h>
#include <hip/hip_fp16.h>

#define NN 100000
#define NE 1600000
#define NB 391        // node buckets: node >> 8 (256 nodes/bucket, last=160)
#define NBLK 391      // edge chunks of CHUNK
#define CHUNK 4096
#define BT 1024       // k_bucket block size
#define PT 1024       // k_p2 block size
#define ASTR 8192     // arena stride/bucket; counts ~Bin(1.6M,256/1e5):
                      // mean 4096, sd 64 -> 8192 is +64 sd, cannot overflow

// ---- fp16 helpers ----------------------------------------------------------
__device__ __forceinline__ float h16lo(unsigned u) {
    return __half2float(__ushort_as_half((unsigned short)(u & 0xffffu)));
}
__device__ __forceinline__ float h16hi(unsigned u) {
    return __half2float(__ushort_as_half((unsigned short)(u >> 16)));
}
__device__ __forceinline__ unsigned short h16(float f) {
    return __half_as_ushort(__float2half(f));
}
__device__ __forceinline__ unsigned pack2h(float a, float b) {
    return (unsigned)h16(a) | ((unsigned)h16(b) << 16);
}
__device__ __forceinline__ __half2 u2h2(unsigned u) {
    union { unsigned u; __half2 h; } cv; cv.u = u; return cv.h;
}

using f16x8  = __attribute__((ext_vector_type(8)))  _Float16;
using f32x16 = __attribute__((ext_vector_type(16))) float;

// ---------------------------------------------------------------------------
// K0: zero the 784 cursor ints (native; hipMemsetAsync's fillBuffer costs
// a full dispatch).
// ---------------------------------------------------------------------------
__global__ __launch_bounds__(1024) void k_zero(int* __restrict__ p) {
    int i = threadIdx.x;
    if (i < 784) p[i] = 0;
}

// ---------------------------------------------------------------------------
// B1: fused count + LDS counting-sort + coalesced arena write (R12/R14/R16).
// ---------------------------------------------------------------------------
__global__ __launch_bounds__(BT) void k_bucket(
        const int* __restrict__ src, const int* __restrict__ dst,
        int* __restrict__ cur_d, int* __restrict__ cur_s,
        unsigned* __restrict__ bkd, unsigned char* __restrict__ bks) {
    __shared__ int hd[NB], hs[NB];            // hist, then LDS cursors
    __shared__ int bd[NB], bs[NB];            // claimed global bases
    __shared__ int od[NB], os[NB];            // local exclusive offsets
    __shared__ int t0[512], t1[512];          // scan temps
    __shared__ unsigned       sortd[CHUNK];   // dst-sorted packed entries
    __shared__ unsigned short sbkt [CHUNK];   // bucket id per entry (dst)
    __shared__ unsigned char  sorts[CHUNK];   // src-sorted bytes
    __shared__ unsigned short sbkts[CHUNK];   // bucket id per entry (src)

    int tid = threadIdx.x, blk = blockIdx.x;
    if (tid < NB) { hd[tid] = 0; hs[tid] = 0; }
    __syncthreads();

    int e0 = blk * CHUNK, ee = min(e0 + CHUNK, NE);
    int sv[4], dv[4]; bool va[4];
#pragma unroll
    for (int u = 0; u < 4; ++u) {
        int e = e0 + u * BT + tid;
        va[u] = e < ee;
        if (va[u]) {
            sv[u] = src[e]; dv[u] = dst[e];
            atomicAdd(&hd[dv[u] >> 8], 1);
            atomicAdd(&hs[sv[u] >> 8], 1);
        }
    }
    __syncthreads();

    if (tid < 512) {
        t0[tid] = tid < NB ? hd[tid] : 0;
        t1[tid] = tid < NB ? hs[tid] : 0;
    }
    __syncthreads();
    for (int off = 1; off < 512; off <<= 1) {
        int a = 0, b = 0;
        if (tid < 512 && tid >= off) { a = t0[tid - off]; b = t1[tid - off]; }
        __syncthreads();
        if (tid < 512) { t0[tid] += a; t1[tid] += b; }
        __syncthreads();
    }
    if (tid < NB) {
        int c = hd[tid], c2 = hs[tid];
        od[tid] = t0[tid] - c;
        os[tid] = t1[tid] - c2;
        bd[tid] = c  ? atomicAdd(&cur_d[tid], c)  : 0;
        bs[tid] = c2 ? atomicAdd(&cur_s[tid], c2) : 0;
        hd[tid] = od[tid];            // reuse as LDS cursors
        hs[tid] = os[tid];
    }
    __syncthreads();

#pragma unroll
    for (int u = 0; u < 4; ++u) if (va[u]) {
        int bu = dv[u] >> 8;
        int p = atomicAdd(&hd[bu], 1);
        sortd[p] = ((unsigned)(dv[u] & 255) << 17) | (unsigned)sv[u];
        sbkt[p]  = (unsigned short)bu;
        int bv = sv[u] >> 8;
        int q = atomicAdd(&hs[bv], 1);
        sorts[q] = (unsigned char)(sv[u] & 255);
        sbkts[q] = (unsigned short)bv;
    }
    __syncthreads();

    int n = ee - e0;
    for (int i = tid; i < n; i += BT) {
        int b1 = sbkt[i];
        bkd[b1 * ASTR + bd[b1] + (i - od[b1])] = sortd[i];
        int b2 = sbkts[i];
        bks[b2 * ASTR + bs[b2] + (i - os[b2])] = sorts[i];
    }
}

// ---------------------------------------------------------------------------
// B2 (FUSED scanb+p2d+p2s+norm), 1024 threads (R13/R14/R16, passing).
// ---------------------------------------------------------------------------
__global__ __launch_bounds__(PT) void k_p2(const unsigned* __restrict__ bkd,
                                           const unsigned char* __restrict__ bks,
                                           const int* __restrict__ cur_d,
                                           const int* __restrict__ cur_s,
                                           int* __restrict__ cd,
                                           int* __restrict__ start,
                                           int* __restrict__ csr_s,
                                           float* __restrict__ dis,
                                           float* __restrict__ disg) {
    __shared__ int hist[256], scn[256], hsA[256];
    __shared__ int red[PT];
    int b = blockIdx.x, tid = threadIdx.x;
    if (tid < 256) { hist[tid] = 0; hsA[tid] = 0; }
    int acc = 0;
    for (int i = tid; i < b; i += PT) acc += cur_d[i];
    red[tid] = acc;
    __syncthreads();
    for (int off = PT / 2; off > 0; off >>= 1) {
        if (tid < off) red[tid] += red[tid + off];
        __syncthreads();
    }
    int cb = red[0];

    int eb = b * ASTR, ee = eb + cur_d[b];
    for (int e = eb + tid; e < ee; e += PT)
        atomicAdd(&hist[bkd[e] >> 17], 1);
    int sb = b * ASTR, se = sb + cur_s[b];
    for (int e = sb + tid; e < se; e += PT)
        atomicAdd(&hsA[bks[e]], 1);
    __syncthreads();
    int c = (tid < 256) ? hist[tid] : 0;
    if (tid < 256) scn[tid] = c;
    __syncthreads();
    for (int off = 1; off < 256; off <<= 1) {
        int t = (tid < 256 && tid >= off) ? scn[tid - off] : 0;
        __syncthreads();
        if (tid < 256) scn[tid] += t;
        __syncthreads();
    }
    if (tid < 256) {
        int excl = scn[tid] - c;
        int node = (b << 8) + tid;
        if (node < NN) {
            cd[node] = c;
            start[node] = cb + excl;
            int oc = hsA[tid];
            dis[node]  = oc > 0 ? rsqrtf((float)oc) : 0.0f;
            disg[node] = rsqrtf((float)c + 1.0f);
        }
    }
    __syncthreads();              // all hsA reads done
    if (tid < 256) hsA[tid] = cb + scn[tid] - c;   // reuse as csr cursor
    __syncthreads();
    for (int e = eb + tid; e < ee; e += PT) {
        unsigned pk = bkd[e];
        int p = atomicAdd(&hsA[pk >> 17], 1);
        csr_s[p] = (int)(pk & 0x1FFFFu);
    }
}

// ---------------------------------------------------------------------------
// K_cvt (+wcvt in the extra block): SINGLE merged fp16 table (R14, passing).
// ---------------------------------------------------------------------------
__global__ __launch_bounds__(256) void k_cvt(const float* __restrict__ x,
                                             const float* __restrict__ dis,
                                             unsigned short* __restrict__ xs,
                                             const float* __restrict__ W_xz,
                                             const float* __restrict__ W_xh,
                                             const float* __restrict__ W_gcn,
                                             unsigned short* __restrict__ BzT,
                                             unsigned short* __restrict__ BhT,
                                             unsigned short* __restrict__ WgT) {
    int tid = threadIdx.x;
    int i = blockIdx.x * 256 + tid;
    if (i < NN * 32) {
        xs[i] = h16(x[i] * dis[i >> 5]);
    } else if (blockIdx.x == (NN * 32) / 256) {
        for (int idx = tid; idx < 2048; idx += 256) {
            int f = idx >> 6, k = idx & 63;
            float vz = (k < 32) ? W_xz[k * 32 + f] : W_xz[1024 + (k - 32) * 32 + f];
            float vh = (k < 32) ? W_xh[k * 32 + f] : W_xh[1024 + (k - 32) * 32 + f];
            BzT[idx] = h16(vz);
            BhT[idx] = h16(vh);
        }
        for (int idx = tid; idx < 1024; idx += 256) {
            int f = idx >> 5, k = idx & 31;
            WgT[idx] = h16(W_gcn[k * 32 + f]);
        }
    }
}

// ---------------------------------------------------------------------------
// K_lxdmm (FUSED gather_lx + dmm): grid NN/32 blocks x 256 threads.
// Phase 1 (all 4 waves): 8 lane-groups gather Lx for 4 nodes each (packed
//   fp16 main loop, masked f32 tail) -> LDS tile LxL[32][20] uints (80B
//   rows: 16B-aligned f16x8 fragments, <=4-way bank aliasing).
// Phase 2 (wave 0 only): k_dmm MFMA pipeline for the block's 32 nodes,
//   Lx A-fragments read from LDS.  Lxh global round-trip eliminated.
// ---------------------------------------------------------------------------
__global__ __launch_bounds__(256) void k_lxdmm(
        const uint2* __restrict__ xs2,
        const int* __restrict__ csr_s,
        const int* __restrict__ start, const int* __restrict__ cd,
        const float* __restrict__ dis, const float* __restrict__ x,
        const f16x8* __restrict__ BzT,
        const f16x8* __restrict__ BhT,
        const f16x8* __restrict__ WgT,
        const float* __restrict__ b_xz, const float* __restrict__ b_hz,
        const float* __restrict__ b_xh, const float* __restrict__ b_hh,
        const float* __restrict__ disg,
        unsigned short* __restrict__ hws) {
    __shared__ __align__(16) unsigned LxL[32 * 20];      // 32 rows x 80B
    __shared__ __align__(16) unsigned short Hw[1280];    // 32 x 40 u16
    int tid = threadIdx.x, blk = blockIdx.x;
    int n0 = blk * 32;
    int grp = tid >> 5, lane = tid & 31, eoff = lane >> 3, c = lane & 7;

    // ---- phase 1: gather Lx rows ----
#pragma unroll 1
    for (int b = 0; b < 4; ++b) {
        int nl = b * 8 + grp;
        int node = n0 + nl;
        int st = start[node], cn = cd[node];
        float a0 = 0.f, a1 = 0.f, a2 = 0.f, a3 = 0.f;
        int j = 0;
        for (; j + 16 <= cn; j += 16) {        // unmasked, packed-fp16
            int s0 = csr_s[st + j + eoff];
            int s1 = csr_s[st + j + 4 + eoff];
            int s2 = csr_s[st + j + 8 + eoff];
            int s3 = csr_s[st + j + 12 + eoff];
            uint2 v0 = xs2[s0 * 8 + c];
            uint2 v1 = xs2[s1 * 8 + c];
            uint2 v2 = xs2[s2 * 8 + c];
            uint2 v3 = xs2[s3 * 8 + c];
            __half2 p01 = u2h2(0u), p23 = u2h2(0u);
            p01 = __hadd2(p01, u2h2(v0.x));  p23 = __hadd2(p23, u2h2(v0.y));
            p01 = __hadd2(p01, u2h2(v1.x));  p23 = __hadd2(p23, u2h2(v1.y));
            p01 = __hadd2(p01, u2h2(v2.x));  p23 = __hadd2(p23, u2h2(v2.y));
            p01 = __hadd2(p01, u2h2(v3.x));  p23 = __hadd2(p23, u2h2(v3.y));
            a0 += __low2float(p01);  a1 += __high2float(p01);
            a2 += __low2float(p23);  a3 += __high2float(p23);
        }
        while (j < cn) {                       // masked f32 tail
            int e0 = j + eoff, e1 = j + 4 + eoff;
            int c0 = e0 < cn ? e0 : cn - 1;  float m0 = e0 < cn ? 1.0f : 0.0f;
            int c1 = e1 < cn ? e1 : cn - 1;  float m1 = e1 < cn ? 1.0f : 0.0f;
            int s0 = csr_s[st + c0], s1 = csr_s[st + c1];
            uint2 v0 = xs2[s0 * 8 + c];
            uint2 v1 = xs2[s1 * 8 + c];
            a0 = fmaf(m0, h16lo(v0.x), a0);  a1 = fmaf(m0, h16hi(v0.x), a1);
            a2 = fmaf(m0, h16lo(v0.y), a2);  a3 = fmaf(m0, h16hi(v0.y), a3);
            a0 = fmaf(m1, h16lo(v1.x), a0);  a1 = fmaf(m1, h16hi(v1.x), a1);
            a2 = fmaf(m1, h16lo(v1.y), a2);  a3 = fmaf(m1, h16hi(v1.y), a3);
            j += 8;
        }
#pragma unroll
        for (int off = 8; off < 32; off <<= 1) {
            a0 += __shfl_xor(a0, off, 32);  a1 += __shfl_xor(a1, off, 32);
            a2 += __shfl_xor(a2, off, 32);  a3 += __shfl_xor(a3, off, 32);
        }
        if (lane < 8) {      // c == lane; features 4c..4c+3
            float w = -dis[node];
            LxL[nl * 20 + 2 * lane]     = pack2h(w * a0, w * a1);
            LxL[nl * 20 + 2 * lane + 1] = pack2h(w * a2, w * a3);
        }
    }
    __syncthreads();
    if (tid >= 64) return;     // waves 1-3 retire

    // ---- phase 2: dense MFMA (wave 0, 32 nodes) ----
    int mrow = tid & 31, hi = tid >> 5;
    f32x16 accz = {}, acct = {};
    const float* xrow = x + (size_t)(n0 + mrow) * 32;
#pragma unroll
    for (int cc = 0; cc < 2; ++cc) {
        f16x8 a;
        const float* p = xrow + cc * 16 + hi * 8;
#pragma unroll
        for (int e = 0; e < 8; ++e) a[e] = (_Float16)p[e];
        accz = __builtin_amdgcn_mfma_f32_32x32x16_f16(a, BzT[mrow * 8 + cc * 2 + hi], accz, 0, 0, 0);
        acct = __builtin_amdgcn_mfma_f32_32x32x16_f16(a, BhT[mrow * 8 + cc * 2 + hi], acct, 0, 0, 0);
    }
#pragma unroll
    for (int cc = 2; cc < 4; ++cc) {
        f16x8 a = *reinterpret_cast<const f16x8*>(&LxL[mrow * 20 + (cc - 2) * 8 + hi * 4]);
        accz = __builtin_amdgcn_mfma_f32_32x32x16_f16(a, BzT[mrow * 8 + cc * 2 + hi], accz, 0, 0, 0);
        acct = __builtin_amdgcn_mfma_f32_32x32x16_f16(a, BhT[mrow * 8 + cc * 2 + hi], acct, 0, 0, 0);
    }
    float bz = b_xz[mrow] + b_hz[mrow];
    float bh = b_xh[mrow] + b_hh[mrow];
#pragma unroll
    for (int j = 0; j < 16; ++j) {
        float z = accz[j] + bz, t = acct[j] + bh;
        float Z = 1.0f / (1.0f + expf(-z));
        float H = (1.0f - Z) * tanhf(t);
        int r = (j & 3) + 8 * (j >> 2) + 4 * hi;
        Hw[r * 40 + mrow] = h16(H);          // H^T staging (row=node, col=f)
    }
    f32x16 acch = {};
#pragma unroll
    for (int cc = 0; cc < 2; ++cc) {
        f16x8 hfrag = *reinterpret_cast<const f16x8*>(&Hw[mrow * 40 + cc * 16 + hi * 8]);
        acch = __builtin_amdgcn_mfma_f32_32x32x16_f16(hfrag, WgT[mrow * 4 + cc * 2 + hi], acch, 0, 0, 0);
    }
#pragma unroll
    for (int j = 0; j < 16; ++j) {
        int r = (j & 3) + 8 * (j >> 2) + 4 * hi;
        int node = n0 + r;
        hws[node * 32 + mrow] = h16(disg[node] * acch[j]);
    }
}

// ---------------------------------------------------------------------------
// K_gath_h: merged gather + full fused epilogue; packed-fp16 main loop
// (R17, passing).
// ---------------------------------------------------------------------------
__global__ __launch_bounds__(256) void k_gath_h(const uint2* __restrict__ hws2,
                                                const int* __restrict__ csr_s,
                                                const int* __restrict__ start,
                                                const int* __restrict__ cd,
                                                const float* __restrict__ disg,
                                                const float* __restrict__ b_gcn,
                                                const float* __restrict__ W_lin,
                                                const float* __restrict__ b_lin,
                                                float* __restrict__ out) {
    int tid = threadIdx.x;
    int node = blockIdx.x * 8 + (tid >> 5);
    int lane = tid & 31, eoff = lane >> 3, c = lane & 7;
    int st = start[node], cn = cd[node];

    float a0 = 0.f, a1 = 0.f, a2 = 0.f, a3 = 0.f;
    int j = 0;
    for (; j + 16 <= cn; j += 16) {        // unmasked, packed-fp16 partials
        int s0 = csr_s[st + j + eoff];
        int s1 = csr_s[st + j + 4 + eoff];
        int s2 = csr_s[st + j + 8 + eoff];
        int s3 = csr_s[st + j + 12 + eoff];
        uint2 v0 = hws2[s0 * 8 + c];
        uint2 v1 = hws2[s1 * 8 + c];
        uint2 v2 = hws2[s2 * 8 + c];
        uint2 v3 = hws2[s3 * 8 + c];
        __half2 p01 = u2h2(0u), p23 = u2h2(0u);
        p01 = __hadd2(p01, u2h2(v0.x));  p23 = __hadd2(p23, u2h2(v0.y));
        p01 = __hadd2(p01, u2h2(v1.x));  p23 = __hadd2(p23, u2h2(v1.y));
        p01 = __hadd2(p01, u2h2(v2.x));  p23 = __hadd2(p23, u2h2(v2.y));
        p01 = __hadd2(p01, u2h2(v3.x));  p23 = __hadd2(p23, u2h2(v3.y));
        a0 += __low2float(p01);  a1 += __high2float(p01);
        a2 += __low2float(p23);  a3 += __high2float(p23);
    }
    while (j < cn) {                       // masked f32 tail (<=2 batches)
        int e0 = j + eoff, e1 = j + 4 + eoff;
        int c0 = e0 < cn ? e0 : cn - 1;  float m0 = e0 < cn ? 1.0f : 0.0f;
        int c1 = e1 < cn ? e1 : cn - 1;  float m1 = e1 < cn ? 1.0f : 0.0f;
        int s0 = csr_s[st + c0], s1 = csr_s[st + c1];
        uint2 v0 = hws2[s0 * 8 + c];
        uint2 v1 = hws2[s1 * 8 + c];
        a0 = fmaf(m0, h16lo(v0.x), a0);  a1 = fmaf(m0, h16hi(v0.x), a1);
        a2 = fmaf(m0, h16lo(v0.y), a2);  a3 = fmaf(m0, h16hi(v0.y), a3);
        a0 = fmaf(m1, h16lo(v1.x), a0);  a1 = fmaf(m1, h16hi(v1.x), a1);
        a2 = fmaf(m1, h16lo(v1.y), a2);  a3 = fmaf(m1, h16hi(v1.y), a3);
        j += 8;
    }
#pragma unroll
    for (int off = 8; off < 32; off <<= 1) {
        a0 += __shfl_xor(a0, off, 32);  a1 += __shfl_xor(a1, off, 32);
        a2 += __shfl_xor(a2, off, 32);  a3 += __shfl_xor(a3, off, 32);
    }
    float p = 0.0f;
    if (lane < 8) {      // c == lane; features f0 = 4c
        uint2 sv = hws2[node * 8 + lane];   // self row (pre-scaled by disg)
        float dg = disg[node];
        int f0 = 4 * lane;
        float h0 = dg * (a0 + h16lo(sv.x)) + b_gcn[f0];
        float h1 = dg * (a1 + h16hi(sv.x)) + b_gcn[f0 + 1];
        float h2 = dg * (a2 + h16lo(sv.y)) + b_gcn[f0 + 2];
        float h3 = dg * (a3 + h16hi(sv.y)) + b_gcn[f0 + 3];
        p = fmaxf(h0, 0.0f) * W_lin[f0]
          + fmaxf(h1, 0.0f) * W_lin[f0 + 1]
          + fmaxf(h2, 0.0f) * W_lin[f0 + 2]
          + fmaxf(h3, 0.0f) * W_lin[f0 + 3];
    }
    p += __shfl_xor(p, 1, 32);
    p += __shfl_xor(p, 2, 32);
    p += __shfl_xor(p, 4, 32);
    if (lane == 0) out[node] = p + b_lin[0];
}

extern "C" void kernel_launch(void* const* d_in, const int* in_sizes, int n_in,
                              void* d_out, int out_size, void* d_ws, size_t ws_size,
                              hipStream_t stream) {
    const float* x     = (const float*)d_in[0];
    const int*   ei    = (const int*)d_in[1];
    const int*   src   = ei;
    const int*   dst   = ei + NE;
    const float* W_xz  = (const float*)d_in[2];
    const float* b_xz  = (const float*)d_in[3];
    const float* b_hz  = (const float*)d_in[5];
    // W_xr/b_xr/W_hr/b_hr (d_in[6..9]) are dead: R only multiplies H0 == 0.
    const float* W_xh  = (const float*)d_in[10];
    const float* b_xh  = (const float*)d_in[11];
    const float* b_hh  = (const float*)d_in[13];
    const float* W_gcn = (const float*)d_in[14];
    const float* b_gcn = (const float*)d_in[15];
    const float* W_lin = (const float*)d_in[16];
    const float* b_lin = (const float*)d_in[17];
    float* out = (float*)d_out;

    // Workspace (4B words), ~30.4 MB (Lxh deleted).  cur_d/cur_s zeroed by
    // k_zero.  Aliases: xs (16N words) overlays bkd arena (dead after k_p2).
    // Alignment audit: hws @400,784 w -> 1,603,136 B (%8==0 for uint2);
    //   bkd/xs @2,000,784 w -> 8,003,136 B (%8==0);
    //   BzT @7,604,624 w -> 30,418,496 B (%16==0 for f16x8);
    //   BhT +4096 B, WgT +4096 B (%16==0).
    // Sizes (R9 lesson): BzT/BhT = 1024 words (2048 ushorts), WgT = 512.
    int* w = (int*)d_ws;
    int* cur_d = w;                       w += 392;
    int* cur_s = w;                       w += 392;
    int* cd    = w;                       w += NN;
    int* start = w;                       w += NN;
    float* dis  = (float*)w;              w += NN;
    float* disg = (float*)w;              w += NN;
    unsigned short* hws = (unsigned short*)w;  w += 16 * NN;    // 32 fp16/node
    unsigned* bkd = (unsigned*)w;         w += NB * ASTR;       // 3,203,072
    unsigned char* bks = (unsigned char*)w; w += (NB * ASTR) / 4;
    int* csr_s = w;                       w += NE;
    unsigned short* BzT = (unsigned short*)w; w += 1024;        // 32f x 64k
    unsigned short* BhT = (unsigned short*)w; w += 1024;
    unsigned short* WgT = (unsigned short*)w; w += 512;         // 32f x 32k
    unsigned short* xs = (unsigned short*)bkd;                  // alias

    k_zero   <<<1, 1024, 0, stream>>>(cur_d);
    k_bucket <<<NBLK, BT, 0, stream>>>(src, dst, cur_d, cur_s, bkd, bks);
    k_p2     <<<NB, PT, 0, stream>>>(bkd, bks, cur_d, cur_s,
                                     cd, start, csr_s, dis, disg);
    k_cvt    <<<(NN * 32) / 256 + 1, 256, 0, stream>>>(x, dis, xs,
                                      W_xz, W_xh, W_gcn, BzT, BhT, WgT);
    k_lxdmm  <<<NN / 32, 256, 0, stream>>>((const uint2*)xs, csr_s, start, cd,
                                           dis, x, (const f16x8*)BzT,
                                           (const f16x8*)BhT, (const f16x8*)WgT,
                                           b_xz, b_hz, b_xh, b_hh, disg, hws);
    k_gath_h <<<NN / 8, 256, 0, stream>>>((const uint2*)hws, csr_s, start, cd,
                                          disg, b_gcn, W_lin, b_lin, out);
}

// Round 19
// 118.829 us; speedup vs baseline: 1.0640x; 1.0640x over previous
//
#include <hip/hip_runtime.h>
#include <hip/hip_fp16.h>

#define NN 100000
#define NE 1600000
#define NB 391        // node buckets: node >> 8 (256 nodes/bucket, last=160)
#define NBLK 391      // edge chunks of CHUNK
#define CHUNK 4096
#define BT 1024       // k_bucket block size
#define PT 1024       // k_p2 block size
#define ASTR 8192     // arena stride/bucket; counts ~Bin(1.6M,256/1e5):
                      // mean 4096, sd 64 -> 8192 is +64 sd, cannot overflow

// ---- fp16 helpers ----------------------------------------------------------
__device__ __forceinline__ float h16lo(unsigned u) {
    return __half2float(__ushort_as_half((unsigned short)(u & 0xffffu)));
}
__device__ __forceinline__ float h16hi(unsigned u) {
    return __half2float(__ushort_as_half((unsigned short)(u >> 16)));
}
__device__ __forceinline__ unsigned short h16(float f) {
    return __half_as_ushort(__float2half(f));
}
__device__ __forceinline__ unsigned pack2h(float a, float b) {
    return (unsigned)h16(a) | ((unsigned)h16(b) << 16);
}
__device__ __forceinline__ __half2 u2h2(unsigned u) {
    union { unsigned u; __half2 h; } cv; cv.u = u; return cv.h;
}

using f16x8  = __attribute__((ext_vector_type(8)))  _Float16;
using f32x16 = __attribute__((ext_vector_type(16))) float;

// ---------------------------------------------------------------------------
// K0: zero the 784 cursor ints AND build the fp16 transposed weight tables
// (no dependencies; runs at stream head on 1 block's idle threads).
// ---------------------------------------------------------------------------
__global__ __launch_bounds__(1024) void k_zero(int* __restrict__ p,
                                               const float* __restrict__ W_xz,
                                               const float* __restrict__ W_xh,
                                               const float* __restrict__ W_gcn,
                                               unsigned short* __restrict__ BzT,
                                               unsigned short* __restrict__ BhT,
                                               unsigned short* __restrict__ WgT) {
    int tid = threadIdx.x;
    if (tid < 784) p[tid] = 0;
    for (int idx = tid; idx < 2048; idx += 1024) {
        int f = idx >> 6, k = idx & 63;
        float vz = (k < 32) ? W_xz[k * 32 + f] : W_xz[1024 + (k - 32) * 32 + f];
        float vh = (k < 32) ? W_xh[k * 32 + f] : W_xh[1024 + (k - 32) * 32 + f];
        BzT[idx] = h16(vz);
        BhT[idx] = h16(vh);
    }
    for (int idx = tid; idx < 1024; idx += 1024) {
        int f = idx >> 5, k = idx & 31;
        WgT[idx] = h16(W_gcn[k * 32 + f]);
    }
}

// ---------------------------------------------------------------------------
// B1: fused count + LDS counting-sort + coalesced arena write (R12/R14/R16).
// ---------------------------------------------------------------------------
__global__ __launch_bounds__(BT) void k_bucket(
        const int* __restrict__ src, const int* __restrict__ dst,
        int* __restrict__ cur_d, int* __restrict__ cur_s,
        unsigned* __restrict__ bkd, unsigned char* __restrict__ bks) {
    __shared__ int hd[NB], hs[NB];            // hist, then LDS cursors
    __shared__ int bd[NB], bs[NB];            // claimed global bases
    __shared__ int od[NB], os[NB];            // local exclusive offsets
    __shared__ int t0[512], t1[512];          // scan temps
    __shared__ unsigned       sortd[CHUNK];   // dst-sorted packed entries
    __shared__ unsigned short sbkt [CHUNK];   // bucket id per entry (dst)
    __shared__ unsigned char  sorts[CHUNK];   // src-sorted bytes
    __shared__ unsigned short sbkts[CHUNK];   // bucket id per entry (src)

    int tid = threadIdx.x, blk = blockIdx.x;
    if (tid < NB) { hd[tid] = 0; hs[tid] = 0; }
    __syncthreads();

    int e0 = blk * CHUNK, ee = min(e0 + CHUNK, NE);
    int sv[4], dv[4]; bool va[4];
#pragma unroll
    for (int u = 0; u < 4; ++u) {
        int e = e0 + u * BT + tid;
        va[u] = e < ee;
        if (va[u]) {
            sv[u] = src[e]; dv[u] = dst[e];
            atomicAdd(&hd[dv[u] >> 8], 1);
            atomicAdd(&hs[sv[u] >> 8], 1);
        }
    }
    __syncthreads();

    if (tid < 512) {
        t0[tid] = tid < NB ? hd[tid] : 0;
        t1[tid] = tid < NB ? hs[tid] : 0;
    }
    __syncthreads();
    for (int off = 1; off < 512; off <<= 1) {
        int a = 0, b = 0;
        if (tid < 512 && tid >= off) { a = t0[tid - off]; b = t1[tid - off]; }
        __syncthreads();
        if (tid < 512) { t0[tid] += a; t1[tid] += b; }
        __syncthreads();
    }
    if (tid < NB) {
        int c = hd[tid], c2 = hs[tid];
        od[tid] = t0[tid] - c;
        os[tid] = t1[tid] - c2;
        bd[tid] = c  ? atomicAdd(&cur_d[tid], c)  : 0;
        bs[tid] = c2 ? atomicAdd(&cur_s[tid], c2) : 0;
        hd[tid] = od[tid];            // reuse as LDS cursors
        hs[tid] = os[tid];
    }
    __syncthreads();

#pragma unroll
    for (int u = 0; u < 4; ++u) if (va[u]) {
        int bu = dv[u] >> 8;
        int p = atomicAdd(&hd[bu], 1);
        sortd[p] = ((unsigned)(dv[u] & 255) << 17) | (unsigned)sv[u];
        sbkt[p]  = (unsigned short)bu;
        int bv = sv[u] >> 8;
        int q = atomicAdd(&hs[bv], 1);
        sorts[q] = (unsigned char)(sv[u] & 255);
        sbkts[q] = (unsigned short)bv;
    }
    __syncthreads();

    int n = ee - e0;
    for (int i = tid; i < n; i += BT) {
        int b1 = sbkt[i];
        bkd[b1 * ASTR + bd[b1] + (i - od[b1])] = sortd[i];
        int b2 = sbkts[i];
        bks[b2 * ASTR + bs[b2] + (i - os[b2])] = sorts[i];
    }
}

// ---------------------------------------------------------------------------
// B2 (FUSED scanb+p2d+p2s+norm), 1024 threads (R13/R14/R16, passing).
// ---------------------------------------------------------------------------
__global__ __launch_bounds__(PT) void k_p2(const unsigned* __restrict__ bkd,
                                           const unsigned char* __restrict__ bks,
                                           const int* __restrict__ cur_d,
                                           const int* __restrict__ cur_s,
                                           int* __restrict__ cd,
                                           int* __restrict__ start,
                                           int* __restrict__ csr_s,
                                           float* __restrict__ dis,
                                           float* __restrict__ disg) {
    __shared__ int hist[256], scn[256], hsA[256];
    __shared__ int red[PT];
    int b = blockIdx.x, tid = threadIdx.x;
    if (tid < 256) { hist[tid] = 0; hsA[tid] = 0; }
    int acc = 0;
    for (int i = tid; i < b; i += PT) acc += cur_d[i];
    red[tid] = acc;
    __syncthreads();
    for (int off = PT / 2; off > 0; off >>= 1) {
        if (tid < off) red[tid] += red[tid + off];
        __syncthreads();
    }
    int cb = red[0];

    int eb = b * ASTR, ee = eb + cur_d[b];
    for (int e = eb + tid; e < ee; e += PT)
        atomicAdd(&hist[bkd[e] >> 17], 1);
    int sb = b * ASTR, se = sb + cur_s[b];
    for (int e = sb + tid; e < se; e += PT)
        atomicAdd(&hsA[bks[e]], 1);
    __syncthreads();
    int c = (tid < 256) ? hist[tid] : 0;
    if (tid < 256) scn[tid] = c;
    __syncthreads();
    for (int off = 1; off < 256; off <<= 1) {
        int t = (tid < 256 && tid >= off) ? scn[tid - off] : 0;
        __syncthreads();
        if (tid < 256) scn[tid] += t;
        __syncthreads();
    }
    if (tid < 256) {
        int excl = scn[tid] - c;
        int node = (b << 8) + tid;
        if (node < NN) {
            cd[node] = c;
            start[node] = cb + excl;
            int oc = hsA[tid];
            dis[node]  = oc > 0 ? rsqrtf((float)oc) : 0.0f;
            disg[node] = rsqrtf((float)c + 1.0f);
        }
    }
    __syncthreads();              // all hsA reads done
    if (tid < 256) hsA[tid] = cb + scn[tid] - c;   // reuse as csr cursor
    __syncthreads();
    for (int e = eb + tid; e < ee; e += PT) {
        unsigned pk = bkd[e];
        int p = atomicAdd(&hsA[pk >> 17], 1);
        csr_s[p] = (int)(pk & 0x1FFFFu);
    }
}

// ---------------------------------------------------------------------------
// K_cvt: xs[node][32] = fp16(dis[node]*x[node][:]) — clean copy kernel.
// ---------------------------------------------------------------------------
__global__ __launch_bounds__(256) void k_cvt(const float* __restrict__ x,
                                             const float* __restrict__ dis,
                                             unsigned short* __restrict__ xs) {
    int i = blockIdx.x * 256 + threadIdx.x;
    if (i < NN * 32) xs[i] = h16(x[i] * dis[i >> 5]);
}

// ---------------------------------------------------------------------------
// K_gath_lx: merged single-pass gather; packed-fp16 main loop (R17, passing).
// ---------------------------------------------------------------------------
__global__ __launch_bounds__(256) void k_gath_lx(const uint2* __restrict__ xs2,
                                                 const int* __restrict__ csr_s,
                                                 const int* __restrict__ start,
                                                 const int* __restrict__ cd,
                                                 const float* __restrict__ dis,
                                                 unsigned* __restrict__ Lxh) {
    int tid = threadIdx.x;
    int node = blockIdx.x * 8 + (tid >> 5);
    int lane = tid & 31, eoff = lane >> 3, c = lane & 7;
    int st = start[node], cn = cd[node];

    float a0 = 0.f, a1 = 0.f, a2 = 0.f, a3 = 0.f;
    int j = 0;
    for (; j + 16 <= cn; j += 16) {        // unmasked, packed-fp16 partials
        int s0 = csr_s[st + j + eoff];
        int s1 = csr_s[st + j + 4 + eoff];
        int s2 = csr_s[st + j + 8 + eoff];
        int s3 = csr_s[st + j + 12 + eoff];
        uint2 v0 = xs2[s0 * 8 + c];
        uint2 v1 = xs2[s1 * 8 + c];
        uint2 v2 = xs2[s2 * 8 + c];
        uint2 v3 = xs2[s3 * 8 + c];
        __half2 p01 = u2h2(0u), p23 = u2h2(0u);
        p01 = __hadd2(p01, u2h2(v0.x));  p23 = __hadd2(p23, u2h2(v0.y));
        p01 = __hadd2(p01, u2h2(v1.x));  p23 = __hadd2(p23, u2h2(v1.y));
        p01 = __hadd2(p01, u2h2(v2.x));  p23 = __hadd2(p23, u2h2(v2.y));
        p01 = __hadd2(p01, u2h2(v3.x));  p23 = __hadd2(p23, u2h2(v3.y));
        a0 += __low2float(p01);  a1 += __high2float(p01);
        a2 += __low2float(p23);  a3 += __high2float(p23);
    }
    while (j < cn) {                       // masked f32 tail (<=2 batches)
        int e0 = j + eoff, e1 = j + 4 + eoff;
        int c0 = e0 < cn ? e0 : cn - 1;  float m0 = e0 < cn ? 1.0f : 0.0f;
        int c1 = e1 < cn ? e1 : cn - 1;  float m1 = e1 < cn ? 1.0f : 0.0f;
        int s0 = csr_s[st + c0], s1 = csr_s[st + c1];
        uint2 v0 = xs2[s0 * 8 + c];
        uint2 v1 = xs2[s1 * 8 + c];
        a0 = fmaf(m0, h16lo(v0.x), a0);  a1 = fmaf(m0, h16hi(v0.x), a1);
        a2 = fmaf(m0, h16lo(v0.y), a2);  a3 = fmaf(m0, h16hi(v0.y), a3);
        a0 = fmaf(m1, h16lo(v1.x), a0);  a1 = fmaf(m1, h16hi(v1.x), a1);
        a2 = fmaf(m1, h16lo(v1.y), a2);  a3 = fmaf(m1, h16hi(v1.y), a3);
        j += 8;
    }
#pragma unroll
    for (int off = 8; off < 32; off <<= 1) {
        a0 += __shfl_xor(a0, off, 32);  a1 += __shfl_xor(a1, off, 32);
        a2 += __shfl_xor(a2, off, 32);  a3 += __shfl_xor(a3, off, 32);
    }
    if (lane < 8) {      // c == lane; features 4c..4c+3
        float w = -dis[node];
        Lxh[node * 16 + 2 * lane]     = pack2h(w * a0, w * a1);
        Lxh[node * 16 + 2 * lane + 1] = pack2h(w * a2, w * a3);
    }
}

// ---------------------------------------------------------------------------
// K_dmm: MFMA dense phase (R14/R16/R17, passing).
// ---------------------------------------------------------------------------
__global__ __launch_bounds__(256) void k_dmm(
        const float* __restrict__ x,
        const f16x8* __restrict__ Lxh,    // [node*4 + (c-2)*2 + hi]
        const f16x8* __restrict__ BzT,
        const f16x8* __restrict__ BhT,
        const f16x8* __restrict__ WgT,
        const float* __restrict__ b_xz, const float* __restrict__ b_hz,
        const float* __restrict__ b_xh, const float* __restrict__ b_hh,
        const float* __restrict__ disg,
        unsigned short* __restrict__ hws) {
    __shared__ unsigned short Hl[4 * 1280];   // per-wave 32 x 40 u16 (80B pad)
    int tid = threadIdx.x;
    int wv = blockIdx.x * 4 + (tid >> 6);
    if (wv > 3124) wv = 3124;                 // dup tail wave: same writes, safe
    int l = tid & 63, mrow = l & 31, hi = l >> 5;
    int n0 = wv * 32;
    unsigned short* Hw = Hl + (tid >> 6) * 1280;

    f32x16 accz = {}, acct = {};
    const float* xrow = x + (size_t)(n0 + mrow) * 32;
#pragma unroll
    for (int c = 0; c < 2; ++c) {
        f16x8 a;
        const float* p = xrow + c * 16 + hi * 8;
#pragma unroll
        for (int e = 0; e < 8; ++e) a[e] = (_Float16)p[e];
        accz = __builtin_amdgcn_mfma_f32_32x32x16_f16(a, BzT[mrow * 8 + c * 2 + hi], accz, 0, 0, 0);
        acct = __builtin_amdgcn_mfma_f32_32x32x16_f16(a, BhT[mrow * 8 + c * 2 + hi], acct, 0, 0, 0);
    }
    const f16x8* Lrow = Lxh + (size_t)(n0 + mrow) * 4;
#pragma unroll
    for (int c = 2; c < 4; ++c) {
        f16x8 a = Lrow[(c - 2) * 2 + hi];
        accz = __builtin_amdgcn_mfma_f32_32x32x16_f16(a, BzT[mrow * 8 + c * 2 + hi], accz, 0, 0, 0);
        acct = __builtin_amdgcn_mfma_f32_32x32x16_f16(a, BhT[mrow * 8 + c * 2 + hi], acct, 0, 0, 0);
    }
    float bz = b_xz[mrow] + b_hz[mrow];
    float bh = b_xh[mrow] + b_hh[mrow];
#pragma unroll
    for (int j = 0; j < 16; ++j) {
        float z = accz[j] + bz, t = acct[j] + bh;
        float Z = 1.0f / (1.0f + expf(-z));
        float H = (1.0f - Z) * tanhf(t);
        int r = (j & 3) + 8 * (j >> 2) + 4 * hi;
        Hw[r * 40 + mrow] = h16(H);          // H^T staging (row=node, col=f)
    }
    f32x16 acch = {};
#pragma unroll
    for (int c = 0; c < 2; ++c) {
        f16x8 hfrag = *reinterpret_cast<const f16x8*>(&Hw[mrow * 40 + c * 16 + hi * 8]);
        acch = __builtin_amdgcn_mfma_f32_32x32x16_f16(hfrag, WgT[mrow * 4 + c * 2 + hi], acch, 0, 0, 0);
    }
#pragma unroll
    for (int j = 0; j < 16; ++j) {
        int r = (j & 3) + 8 * (j >> 2) + 4 * hi;
        int node = n0 + r;
        hws[node * 32 + mrow] = h16(disg[node] * acch[j]);
    }
}

// ---------------------------------------------------------------------------
// K_gath_h: merged gather + full fused epilogue; packed-fp16 main loop
// (R17, passing).
// ---------------------------------------------------------------------------
__global__ __launch_bounds__(256) void k_gath_h(const uint2* __restrict__ hws2,
                                                const int* __restrict__ csr_s,
                                                const int* __restrict__ start,
                                                const int* __restrict__ cd,
                                                const float* __restrict__ disg,
                                                const float* __restrict__ b_gcn,
                                                const float* __restrict__ W_lin,
                                                const float* __restrict__ b_lin,
                                                float* __restrict__ out) {
    int tid = threadIdx.x;
    int node = blockIdx.x * 8 + (tid >> 5);
    int lane = tid & 31, eoff = lane >> 3, c = lane & 7;
    int st = start[node], cn = cd[node];

    float a0 = 0.f, a1 = 0.f, a2 = 0.f, a3 = 0.f;
    int j = 0;
    for (; j + 16 <= cn; j += 16) {        // unmasked, packed-fp16 partials
        int s0 = csr_s[st + j + eoff];
        int s1 = csr_s[st + j + 4 + eoff];
        int s2 = csr_s[st + j + 8 + eoff];
        int s3 = csr_s[st + j + 12 + eoff];
        uint2 v0 = hws2[s0 * 8 + c];
        uint2 v1 = hws2[s1 * 8 + c];
        uint2 v2 = hws2[s2 * 8 + c];
        uint2 v3 = hws2[s3 * 8 + c];
        __half2 p01 = u2h2(0u), p23 = u2h2(0u);
        p01 = __hadd2(p01, u2h2(v0.x));  p23 = __hadd2(p23, u2h2(v0.y));
        p01 = __hadd2(p01, u2h2(v1.x));  p23 = __hadd2(p23, u2h2(v1.y));
        p01 = __hadd2(p01, u2h2(v2.x));  p23 = __hadd2(p23, u2h2(v2.y));
        p01 = __hadd2(p01, u2h2(v3.x));  p23 = __hadd2(p23, u2h2(v3.y));
        a0 += __low2float(p01);  a1 += __high2float(p01);
        a2 += __low2float(p23);  a3 += __high2float(p23);
    }
    while (j < cn) {                       // masked f32 tail (<=2 batches)
        int e0 = j + eoff, e1 = j + 4 + eoff;
        int c0 = e0 < cn ? e0 : cn - 1;  float m0 = e0 < cn ? 1.0f : 0.0f;
        int c1 = e1 < cn ? e1 : cn - 1;  float m1 = e1 < cn ? 1.0f : 0.0f;
        int s0 = csr_s[st + c0], s1 = csr_s[st + c1];
        uint2 v0 = hws2[s0 * 8 + c];
        uint2 v1 = hws2[s1 * 8 + c];
        a0 = fmaf(m0, h16lo(v0.x), a0);  a1 = fmaf(m0, h16hi(v0.x), a1);
        a2 = fmaf(m0, h16lo(v0.y), a2);  a3 = fmaf(m0, h16hi(v0.y), a3);
        a0 = fmaf(m1, h16lo(v1.x), a0);  a1 = fmaf(m1, h16hi(v1.x), a1);
        a2 = fmaf(m1, h16lo(v1.y), a2);  a3 = fmaf(m1, h16hi(v1.y), a3);
        j += 8;
    }
#pragma unroll
    for (int off = 8; off < 32; off <<= 1) {
        a0 += __shfl_xor(a0, off, 32);  a1 += __shfl_xor(a1, off, 32);
        a2 += __shfl_xor(a2, off, 32);  a3 += __shfl_xor(a3, off, 32);
    }
    float p = 0.0f;
    if (lane < 8) {      // c == lane; features f0 = 4c
        uint2 sv = hws2[node * 8 + lane];   // self row (pre-scaled by disg)
        float dg = disg[node];
        int f0 = 4 * lane;
        float h0 = dg * (a0 + h16lo(sv.x)) + b_gcn[f0];
        float h1 = dg * (a1 + h16hi(sv.x)) + b_gcn[f0 + 1];
        float h2 = dg * (a2 + h16lo(sv.y)) + b_gcn[f0 + 2];
        float h3 = dg * (a3 + h16hi(sv.y)) + b_gcn[f0 + 3];
        p = fmaxf(h0, 0.0f) * W_lin[f0]
          + fmaxf(h1, 0.0f) * W_lin[f0 + 1]
          + fmaxf(h2, 0.0f) * W_lin[f0 + 2]
          + fmaxf(h3, 0.0f) * W_lin[f0 + 3];
    }
    p += __shfl_xor(p, 1, 32);
    p += __shfl_xor(p, 2, 32);
    p += __shfl_xor(p, 4, 32);
    if (lane == 0) out[node] = p + b_lin[0];
}

extern "C" void kernel_launch(void* const* d_in, const int* in_sizes, int n_in,
                              void* d_out, int out_size, void* d_ws, size_t ws_size,
                              hipStream_t stream) {
    const float* x     = (const float*)d_in[0];
    const int*   ei    = (const int*)d_in[1];
    const int*   src   = ei;
    const int*   dst   = ei + NE;
    const float* W_xz  = (const float*)d_in[2];
    const float* b_xz  = (const float*)d_in[3];
    const float* b_hz  = (const float*)d_in[5];
    // W_xr/b_xr/W_hr/b_hr (d_in[6..9]) are dead: R only multiplies H0 == 0.
    const float* W_xh  = (const float*)d_in[10];
    const float* b_xh  = (const float*)d_in[11];
    const float* b_hh  = (const float*)d_in[13];
    const float* W_gcn = (const float*)d_in[14];
    const float* b_gcn = (const float*)d_in[15];
    const float* W_lin = (const float*)d_in[16];
    const float* b_lin = (const float*)d_in[17];
    float* out = (float*)d_out;

    // Workspace (4B words), ~36.8 MB (R17 layout, Lxh reinstated).
    // cur_d/cur_s zeroed by k_zero (which also builds weight tables).
    // Aliases: xs (16N words) overlays bkd arena (dead after k_p2).
    int* w = (int*)d_ws;
    int* cur_d = w;                       w += 392;
    int* cur_s = w;                       w += 392;
    int* cd    = w;                       w += NN;
    int* start = w;                       w += NN;
    float* dis  = (float*)w;              w += NN;
    float* disg = (float*)w;              w += NN;
    unsigned short* hws = (unsigned short*)w;  w += 16 * NN;    // 32 fp16/node
    unsigned* Lxh = (unsigned*)w;         w += 16 * NN;         // 32 fp16/node
    unsigned* bkd = (unsigned*)w;         w += NB * ASTR;       // 3,203,072
    unsigned char* bks = (unsigned char*)w; w += (NB * ASTR) / 4;
    int* csr_s = w;                       w += NE;
    unsigned short* BzT = (unsigned short*)w; w += 1024;        // 32f x 64k
    unsigned short* BhT = (unsigned short*)w; w += 1024;
    unsigned short* WgT = (unsigned short*)w; w += 512;         // 32f x 32k
    unsigned short* xs = (unsigned short*)bkd;                  // alias

    k_zero   <<<1, 1024, 0, stream>>>(cur_d, W_xz, W_xh, W_gcn, BzT, BhT, WgT);
    k_bucket <<<NBLK, BT, 0, stream>>>(src, dst, cur_d, cur_s, bkd, bks);
    k_p2     <<<NB, PT, 0, stream>>>(bkd, bks, cur_d, cur_s,
                                     cd, start, csr_s, dis, disg);
    k_cvt    <<<(NN * 32) / 256, 256, 0, stream>>>(x, dis, xs);
    k_gath_lx<<<NN / 8, 256, 0, stream>>>((const uint2*)xs, csr_s, start, cd,
                                          dis, Lxh);
    k_dmm    <<<782, 256, 0, stream>>>(x, (const f16x8*)Lxh, (const f16x8*)BzT,
                                       (const f16x8*)BhT, (const f16x8*)WgT,
                                       b_xz, b_hz, b_xh, b_hh, disg, hws);
    k_gath_h <<<NN / 8, 256, 0, stream>>>((const uint2*)hws, csr_s, start, cd,
                                          disg, b_gcn, W_lin, b_lin, out);
}

// Round 20
// 115.087 us; speedup vs baseline: 1.0986x; 1.0325x over previous
//
#include <hip/hip_runtime.h>
#include <hip/hip_fp16.h>

#define NN 100000
#define NE 1600000
#define NB 391        // node buckets: node >> 8 (256 nodes/bucket, last=160)
#define NBLK 256      // edge chunks: one block per CU (256x6250 = 1.6M exact)
#define CHUNK 6250
#define EPB 7         // ceil(CHUNK / BT)
#define BT 1024       // k_bucket block size
#define PT 1024       // k_p2 block size
#define ASTR 8192     // arena stride/bucket; counts ~Bin(1.6M,256/1e5):
                      // mean 4096, sd 64 -> 8192 is +64 sd, cannot overflow

// ---- fp16 helpers ----------------------------------------------------------
__device__ __forceinline__ float h16lo(unsigned u) {
    return __half2float(__ushort_as_half((unsigned short)(u & 0xffffu)));
}
__device__ __forceinline__ float h16hi(unsigned u) {
    return __half2float(__ushort_as_half((unsigned short)(u >> 16)));
}
__device__ __forceinline__ unsigned short h16(float f) {
    return __half_as_ushort(__float2half(f));
}
__device__ __forceinline__ unsigned pack2h(float a, float b) {
    return (unsigned)h16(a) | ((unsigned)h16(b) << 16);
}
__device__ __forceinline__ __half2 u2h2(unsigned u) {
    union { unsigned u; __half2 h; } cv; cv.u = u; return cv.h;
}

using f16x8  = __attribute__((ext_vector_type(8)))  _Float16;
using f32x16 = __attribute__((ext_vector_type(16))) float;

// ---------------------------------------------------------------------------
// K0: zero the 784 cursor ints AND build the fp16 transposed weight tables.
// ---------------------------------------------------------------------------
__global__ __launch_bounds__(1024) void k_zero(int* __restrict__ p,
                                               const float* __restrict__ W_xz,
                                               const float* __restrict__ W_xh,
                                               const float* __restrict__ W_gcn,
                                               unsigned short* __restrict__ BzT,
                                               unsigned short* __restrict__ BhT,
                                               unsigned short* __restrict__ WgT) {
    int tid = threadIdx.x;
    if (tid < 784) p[tid] = 0;
    for (int idx = tid; idx < 2048; idx += 1024) {
        int f = idx >> 6, k = idx & 63;
        float vz = (k < 32) ? W_xz[k * 32 + f] : W_xz[1024 + (k - 32) * 32 + f];
        float vh = (k < 32) ? W_xh[k * 32 + f] : W_xh[1024 + (k - 32) * 32 + f];
        BzT[idx] = h16(vz);
        BhT[idx] = h16(vh);
    }
    for (int idx = tid; idx < 1024; idx += 1024) {
        int f = idx >> 5, k = idx & 31;
        WgT[idx] = h16(W_gcn[k * 32 + f]);
    }
}

// ---------------------------------------------------------------------------
// B1: fused count + LDS counting-sort + coalesced arena write.
// NBLK=256 / CHUNK=6250: exactly one block per CU (391 blocks left 135 CUs
// running TWO serial blocks = duration setter).  Fixed scan cost now paid
// once per CU; LDS ~70KB/block (fine at 1 block/CU).
// ---------------------------------------------------------------------------
__global__ __launch_bounds__(BT) void k_bucket(
        const int* __restrict__ src, const int* __restrict__ dst,
        int* __restrict__ cur_d, int* __restrict__ cur_s,
        unsigned* __restrict__ bkd, unsigned char* __restrict__ bks) {
    __shared__ int hd[NB], hs[NB];            // hist, then LDS cursors
    __shared__ int bd[NB], bs[NB];            // claimed global bases
    __shared__ int od[NB], os[NB];            // local exclusive offsets
    __shared__ int t0[512], t1[512];          // scan temps
    __shared__ unsigned       sortd[CHUNK];   // dst-sorted packed entries
    __shared__ unsigned short sbkt [CHUNK];   // bucket id per entry (dst)
    __shared__ unsigned char  sorts[CHUNK];   // src-sorted bytes
    __shared__ unsigned short sbkts[CHUNK];   // bucket id per entry (src)

    int tid = threadIdx.x, blk = blockIdx.x;
    if (tid < NB) { hd[tid] = 0; hs[tid] = 0; }
    __syncthreads();

    int e0 = blk * CHUNK;                     // every block has CHUNK edges
    int sv[EPB], dv[EPB]; bool va[EPB];
#pragma unroll
    for (int u = 0; u < EPB; ++u) {
        int o = u * BT + tid;
        va[u] = o < CHUNK;
        if (va[u]) {
            int e = e0 + o;
            sv[u] = src[e]; dv[u] = dst[e];
            atomicAdd(&hd[dv[u] >> 8], 1);
            atomicAdd(&hs[sv[u] >> 8], 1);
        }
    }
    __syncthreads();

    if (tid < 512) {
        t0[tid] = tid < NB ? hd[tid] : 0;
        t1[tid] = tid < NB ? hs[tid] : 0;
    }
    __syncthreads();
    for (int off = 1; off < 512; off <<= 1) {
        int a = 0, b = 0;
        if (tid < 512 && tid >= off) { a = t0[tid - off]; b = t1[tid - off]; }
        __syncthreads();
        if (tid < 512) { t0[tid] += a; t1[tid] += b; }
        __syncthreads();
    }
    if (tid < NB) {
        int c = hd[tid], c2 = hs[tid];
        od[tid] = t0[tid] - c;
        os[tid] = t1[tid] - c2;
        bd[tid] = c  ? atomicAdd(&cur_d[tid], c)  : 0;
        bs[tid] = c2 ? atomicAdd(&cur_s[tid], c2) : 0;
        hd[tid] = od[tid];            // reuse as LDS cursors
        hs[tid] = os[tid];
    }
    __syncthreads();

#pragma unroll
    for (int u = 0; u < EPB; ++u) if (va[u]) {
        int bu = dv[u] >> 8;
        int p = atomicAdd(&hd[bu], 1);
        sortd[p] = ((unsigned)(dv[u] & 255) << 17) | (unsigned)sv[u];
        sbkt[p]  = (unsigned short)bu;
        int bv = sv[u] >> 8;
        int q = atomicAdd(&hs[bv], 1);
        sorts[q] = (unsigned char)(sv[u] & 255);
        sbkts[q] = (unsigned short)bv;
    }
    __syncthreads();

    for (int i = tid; i < CHUNK; i += BT) {
        int b1 = sbkt[i];
        bkd[b1 * ASTR + bd[b1] + (i - od[b1])] = sortd[i];
        int b2 = sbkts[i];
        bks[b2 * ASTR + bs[b2] + (i - os[b2])] = sorts[i];
    }
}

// ---------------------------------------------------------------------------
// B2 (FUSED scanb+p2d+p2s+norm), 1024 threads (R13/R14/R16, passing).
// ---------------------------------------------------------------------------
__global__ __launch_bounds__(PT) void k_p2(const unsigned* __restrict__ bkd,
                                           const unsigned char* __restrict__ bks,
                                           const int* __restrict__ cur_d,
                                           const int* __restrict__ cur_s,
                                           int* __restrict__ cd,
                                           int* __restrict__ start,
                                           int* __restrict__ csr_s,
                                           float* __restrict__ dis,
                                           float* __restrict__ disg) {
    __shared__ int hist[256], scn[256], hsA[256];
    __shared__ int red[PT];
    int b = blockIdx.x, tid = threadIdx.x;
    if (tid < 256) { hist[tid] = 0; hsA[tid] = 0; }
    int acc = 0;
    for (int i = tid; i < b; i += PT) acc += cur_d[i];
    red[tid] = acc;
    __syncthreads();
    for (int off = PT / 2; off > 0; off >>= 1) {
        if (tid < off) red[tid] += red[tid + off];
        __syncthreads();
    }
    int cb = red[0];

    int eb = b * ASTR, ee = eb + cur_d[b];
    for (int e = eb + tid; e < ee; e += PT)
        atomicAdd(&hist[bkd[e] >> 17], 1);
    int sb = b * ASTR, se = sb + cur_s[b];
    for (int e = sb + tid; e < se; e += PT)
        atomicAdd(&hsA[bks[e]], 1);
    __syncthreads();
    int c = (tid < 256) ? hist[tid] : 0;
    if (tid < 256) scn[tid] = c;
    __syncthreads();
    for (int off = 1; off < 256; off <<= 1) {
        int t = (tid < 256 && tid >= off) ? scn[tid - off] : 0;
        __syncthreads();
        if (tid < 256) scn[tid] += t;
        __syncthreads();
    }
    if (tid < 256) {
        int excl = scn[tid] - c;
        int node = (b << 8) + tid;
        if (node < NN) {
            cd[node] = c;
            start[node] = cb + excl;
            int oc = hsA[tid];
            dis[node]  = oc > 0 ? rsqrtf((float)oc) : 0.0f;
            disg[node] = rsqrtf((float)c + 1.0f);
        }
    }
    __syncthreads();              // all hsA reads done
    if (tid < 256) hsA[tid] = cb + scn[tid] - c;   // reuse as csr cursor
    __syncthreads();
    for (int e = eb + tid; e < ee; e += PT) {
        unsigned pk = bkd[e];
        int p = atomicAdd(&hsA[pk >> 17], 1);
        csr_s[p] = (int)(pk & 0x1FFFFu);
    }
}

// ---------------------------------------------------------------------------
// K_cvt: xs[node][32] = fp16(dis[node]*x[node][:]) — clean copy kernel.
// ---------------------------------------------------------------------------
__global__ __launch_bounds__(256) void k_cvt(const float* __restrict__ x,
                                             const float* __restrict__ dis,
                                             unsigned short* __restrict__ xs) {
    int i = blockIdx.x * 256 + threadIdx.x;
    if (i < NN * 32) xs[i] = h16(x[i] * dis[i >> 5]);
}

// ---------------------------------------------------------------------------
// K_gath_lx: merged single-pass gather; packed-fp16 main loop (R17, passing).
// ---------------------------------------------------------------------------
__global__ __launch_bounds__(256) void k_gath_lx(const uint2* __restrict__ xs2,
                                                 const int* __restrict__ csr_s,
                                                 const int* __restrict__ start,
                                                 const int* __restrict__ cd,
                                                 const float* __restrict__ dis,
                                                 unsigned* __restrict__ Lxh) {
    int tid = threadIdx.x;
    int node = blockIdx.x * 8 + (tid >> 5);
    int lane = tid & 31, eoff = lane >> 3, c = lane & 7;
    int st = start[node], cn = cd[node];

    float a0 = 0.f, a1 = 0.f, a2 = 0.f, a3 = 0.f;
    int j = 0;
    for (; j + 16 <= cn; j += 16) {        // unmasked, packed-fp16 partials
        int s0 = csr_s[st + j + eoff];
        int s1 = csr_s[st + j + 4 + eoff];
        int s2 = csr_s[st + j + 8 + eoff];
        int s3 = csr_s[st + j + 12 + eoff];
        uint2 v0 = xs2[s0 * 8 + c];
        uint2 v1 = xs2[s1 * 8 + c];
        uint2 v2 = xs2[s2 * 8 + c];
        uint2 v3 = xs2[s3 * 8 + c];
        __half2 p01 = u2h2(0u), p23 = u2h2(0u);
        p01 = __hadd2(p01, u2h2(v0.x));  p23 = __hadd2(p23, u2h2(v0.y));
        p01 = __hadd2(p01, u2h2(v1.x));  p23 = __hadd2(p23, u2h2(v1.y));
        p01 = __hadd2(p01, u2h2(v2.x));  p23 = __hadd2(p23, u2h2(v2.y));
        p01 = __hadd2(p01, u2h2(v3.x));  p23 = __hadd2(p23, u2h2(v3.y));
        a0 += __low2float(p01);  a1 += __high2float(p01);
        a2 += __low2float(p23);  a3 += __high2float(p23);
    }
    while (j < cn) {                       // masked f32 tail (<=2 batches)
        int e0 = j + eoff, e1 = j + 4 + eoff;
        int c0 = e0 < cn ? e0 : cn - 1;  float m0 = e0 < cn ? 1.0f : 0.0f;
        int c1 = e1 < cn ? e1 : cn - 1;  float m1 = e1 < cn ? 1.0f : 0.0f;
        int s0 = csr_s[st + c0], s1 = csr_s[st + c1];
        uint2 v0 = xs2[s0 * 8 + c];
        uint2 v1 = xs2[s1 * 8 + c];
        a0 = fmaf(m0, h16lo(v0.x), a0);  a1 = fmaf(m0, h16hi(v0.x), a1);
        a2 = fmaf(m0, h16lo(v0.y), a2);  a3 = fmaf(m0, h16hi(v0.y), a3);
        a0 = fmaf(m1, h16lo(v1.x), a0);  a1 = fmaf(m1, h16hi(v1.x), a1);
        a2 = fmaf(m1, h16lo(v1.y), a2);  a3 = fmaf(m1, h16hi(v1.y), a3);
        j += 8;
    }
#pragma unroll
    for (int off = 8; off < 32; off <<= 1) {
        a0 += __shfl_xor(a0, off, 32);  a1 += __shfl_xor(a1, off, 32);
        a2 += __shfl_xor(a2, off, 32);  a3 += __shfl_xor(a3, off, 32);
    }
    if (lane < 8) {      // c == lane; features 4c..4c+3
        float w = -dis[node];
        Lxh[node * 16 + 2 * lane]     = pack2h(w * a0, w * a1);
        Lxh[node * 16 + 2 * lane + 1] = pack2h(w * a2, w * a3);
    }
}

// ---------------------------------------------------------------------------
// K_dmm: MFMA dense phase (R14/R16/R17, passing).
// ---------------------------------------------------------------------------
__global__ __launch_bounds__(256) void k_dmm(
        const float* __restrict__ x,
        const f16x8* __restrict__ Lxh,    // [node*4 + (c-2)*2 + hi]
        const f16x8* __restrict__ BzT,
        const f16x8* __restrict__ BhT,
        const f16x8* __restrict__ WgT,
        const float* __restrict__ b_xz, const float* __restrict__ b_hz,
        const float* __restrict__ b_xh, const float* __restrict__ b_hh,
        const float* __restrict__ disg,
        unsigned short* __restrict__ hws) {
    __shared__ unsigned short Hl[4 * 1280];   // per-wave 32 x 40 u16 (80B pad)
    int tid = threadIdx.x;
    int wv = blockIdx.x * 4 + (tid >> 6);
    if (wv > 3124) wv = 3124;                 // dup tail wave: same writes, safe
    int l = tid & 63, mrow = l & 31, hi = l >> 5;
    int n0 = wv * 32;
    unsigned short* Hw = Hl + (tid >> 6) * 1280;

    f32x16 accz = {}, acct = {};
    const float* xrow = x + (size_t)(n0 + mrow) * 32;
#pragma unroll
    for (int c = 0; c < 2; ++c) {
        f16x8 a;
        const float* p = xrow + c * 16 + hi * 8;
#pragma unroll
        for (int e = 0; e < 8; ++e) a[e] = (_Float16)p[e];
        accz = __builtin_amdgcn_mfma_f32_32x32x16_f16(a, BzT[mrow * 8 + c * 2 + hi], accz, 0, 0, 0);
        acct = __builtin_amdgcn_mfma_f32_32x32x16_f16(a, BhT[mrow * 8 + c * 2 + hi], acct, 0, 0, 0);
    }
    const f16x8* Lrow = Lxh + (size_t)(n0 + mrow) * 4;
#pragma unroll
    for (int c = 2; c < 4; ++c) {
        f16x8 a = Lrow[(c - 2) * 2 + hi];
        accz = __builtin_amdgcn_mfma_f32_32x32x16_f16(a, BzT[mrow * 8 + c * 2 + hi], accz, 0, 0, 0);
        acct = __builtin_amdgcn_mfma_f32_32x32x16_f16(a, BhT[mrow * 8 + c * 2 + hi], acct, 0, 0, 0);
    }
    float bz = b_xz[mrow] + b_hz[mrow];
    float bh = b_xh[mrow] + b_hh[mrow];
#pragma unroll
    for (int j = 0; j < 16; ++j) {
        float z = accz[j] + bz, t = acct[j] + bh;
        float Z = 1.0f / (1.0f + expf(-z));
        float H = (1.0f - Z) * tanhf(t);
        int r = (j & 3) + 8 * (j >> 2) + 4 * hi;
        Hw[r * 40 + mrow] = h16(H);          // H^T staging (row=node, col=f)
    }
    f32x16 acch = {};
#pragma unroll
    for (int c = 0; c < 2; ++c) {
        f16x8 hfrag = *reinterpret_cast<const f16x8*>(&Hw[mrow * 40 + c * 16 + hi * 8]);
        acch = __builtin_amdgcn_mfma_f32_32x32x16_f16(hfrag, WgT[mrow * 4 + c * 2 + hi], acch, 0, 0, 0);
    }
#pragma unroll
    for (int j = 0; j < 16; ++j) {
        int r = (j & 3) + 8 * (j >> 2) + 4 * hi;
        int node = n0 + r;
        hws[node * 32 + mrow] = h16(disg[node] * acch[j]);
    }
}

// ---------------------------------------------------------------------------
// K_gath_h: merged gather + full fused epilogue; packed-fp16 main loop
// (R17, passing).
// ---------------------------------------------------------------------------
__global__ __launch_bounds__(256) void k_gath_h(const uint2* __restrict__ hws2,
                                                const int* __restrict__ csr_s,
                                                const int* __restrict__ start,
                                                const int* __restrict__ cd,
                                                const float* __restrict__ disg,
                                                const float* __restrict__ b_gcn,
                                                const float* __restrict__ W_lin,
                                                const float* __restrict__ b_lin,
                                                float* __restrict__ out) {
    int tid = threadIdx.x;
    int node = blockIdx.x * 8 + (tid >> 5);
    int lane = tid & 31, eoff = lane >> 3, c = lane & 7;
    int st = start[node], cn = cd[node];

    float a0 = 0.f, a1 = 0.f, a2 = 0.f, a3 = 0.f;
    int j = 0;
    for (; j + 16 <= cn; j += 16) {        // unmasked, packed-fp16 partials
        int s0 = csr_s[st + j + eoff];
        int s1 = csr_s[st + j + 4 + eoff];
        int s2 = csr_s[st + j + 8 + eoff];
        int s3 = csr_s[st + j + 12 + eoff];
        uint2 v0 = hws2[s0 * 8 + c];
        uint2 v1 = hws2[s1 * 8 + c];
        uint2 v2 = hws2[s2 * 8 + c];
        uint2 v3 = hws2[s3 * 8 + c];
        __half2 p01 = u2h2(0u), p23 = u2h2(0u);
        p01 = __hadd2(p01, u2h2(v0.x));  p23 = __hadd2(p23, u2h2(v0.y));
        p01 = __hadd2(p01, u2h2(v1.x));  p23 = __hadd2(p23, u2h2(v1.y));
        p01 = __hadd2(p01, u2h2(v2.x));  p23 = __hadd2(p23, u2h2(v2.y));
        p01 = __hadd2(p01, u2h2(v3.x));  p23 = __hadd2(p23, u2h2(v3.y));
        a0 += __low2float(p01);  a1 += __high2float(p01);
        a2 += __low2float(p23);  a3 += __high2float(p23);
    }
    while (j < cn) {                       // masked f32 tail (<=2 batches)
        int e0 = j + eoff, e1 = j + 4 + eoff;
        int c0 = e0 < cn ? e0 : cn - 1;  float m0 = e0 < cn ? 1.0f : 0.0f;
        int c1 = e1 < cn ? e1 : cn - 1;  float m1 = e1 < cn ? 1.0f : 0.0f;
        int s0 = csr_s[st + c0], s1 = csr_s[st + c1];
        uint2 v0 = hws2[s0 * 8 + c];
        uint2 v1 = hws2[s1 * 8 + c];
        a0 = fmaf(m0, h16lo(v0.x), a0);  a1 = fmaf(m0, h16hi(v0.x), a1);
        a2 = fmaf(m0, h16lo(v0.y), a2);  a3 = fmaf(m0, h16hi(v0.y), a3);
        a0 = fmaf(m1, h16lo(v1.x), a0);  a1 = fmaf(m1, h16hi(v1.x), a1);
        a2 = fmaf(m1, h16lo(v1.y), a2);  a3 = fmaf(m1, h16hi(v1.y), a3);
        j += 8;
    }
#pragma unroll
    for (int off = 8; off < 32; off <<= 1) {
        a0 += __shfl_xor(a0, off, 32);  a1 += __shfl_xor(a1, off, 32);
        a2 += __shfl_xor(a2, off, 32);  a3 += __shfl_xor(a3, off, 32);
    }
    float p = 0.0f;
    if (lane < 8) {      // c == lane; features f0 = 4c
        uint2 sv = hws2[node * 8 + lane];   // self row (pre-scaled by disg)
        float dg = disg[node];
        int f0 = 4 * lane;
        float h0 = dg * (a0 + h16lo(sv.x)) + b_gcn[f0];
        float h1 = dg * (a1 + h16hi(sv.x)) + b_gcn[f0 + 1];
        float h2 = dg * (a2 + h16lo(sv.y)) + b_gcn[f0 + 2];
        float h3 = dg * (a3 + h16hi(sv.y)) + b_gcn[f0 + 3];
        p = fmaxf(h0, 0.0f) * W_lin[f0]
          + fmaxf(h1, 0.0f) * W_lin[f0 + 1]
          + fmaxf(h2, 0.0f) * W_lin[f0 + 2]
          + fmaxf(h3, 0.0f) * W_lin[f0 + 3];
    }
    p += __shfl_xor(p, 1, 32);
    p += __shfl_xor(p, 2, 32);
    p += __shfl_xor(p, 4, 32);
    if (lane == 0) out[node] = p + b_lin[0];
}

extern "C" void kernel_launch(void* const* d_in, const int* in_sizes, int n_in,
                              void* d_out, int out_size, void* d_ws, size_t ws_size,
                              hipStream_t stream) {
    const float* x     = (const float*)d_in[0];
    const int*   ei    = (const int*)d_in[1];
    const int*   src   = ei;
    const int*   dst   = ei + NE;
    const float* W_xz  = (const float*)d_in[2];
    const float* b_xz  = (const float*)d_in[3];
    const float* b_hz  = (const float*)d_in[5];
    // W_xr/b_xr/W_hr/b_hr (d_in[6..9]) are dead: R only multiplies H0 == 0.
    const float* W_xh  = (const float*)d_in[10];
    const float* b_xh  = (const float*)d_in[11];
    const float* b_hh  = (const float*)d_in[13];
    const float* W_gcn = (const float*)d_in[14];
    const float* b_gcn = (const float*)d_in[15];
    const float* W_lin = (const float*)d_in[16];
    const float* b_lin = (const float*)d_in[17];
    float* out = (float*)d_out;

    // Workspace (4B words), ~36.8 MB (R19 layout).
    // cur_d/cur_s zeroed by k_zero (which also builds weight tables).
    // Aliases: xs (16N words) overlays bkd arena (dead after k_p2).
    int* w = (int*)d_ws;
    int* cur_d = w;                       w += 392;
    int* cur_s = w;                       w += 392;
    int* cd    = w;                       w += NN;
    int* start = w;                       w += NN;
    float* dis  = (float*)w;              w += NN;
    float* disg = (float*)w;              w += NN;
    unsigned short* hws = (unsigned short*)w;  w += 16 * NN;    // 32 fp16/node
    unsigned* Lxh = (unsigned*)w;         w += 16 * NN;         // 32 fp16/node
    unsigned* bkd = (unsigned*)w;         w += NB * ASTR;       // 3,203,072
    unsigned char* bks = (unsigned char*)w; w += (NB * ASTR) / 4;
    int* csr_s = w;                       w += NE;
    unsigned short* BzT = (unsigned short*)w; w += 1024;        // 32f x 64k
    unsigned short* BhT = (unsigned short*)w; w += 1024;
    unsigned short* WgT = (unsigned short*)w; w += 512;         // 32f x 32k
    unsigned short* xs = (unsigned short*)bkd;                  // alias

    k_zero   <<<1, 1024, 0, stream>>>(cur_d, W_xz, W_xh, W_gcn, BzT, BhT, WgT);
    k_bucket <<<NBLK, BT, 0, stream>>>(src, dst, cur_d, cur_s, bkd, bks);
    k_p2     <<<NB, PT, 0, stream>>>(bkd, bks, cur_d, cur_s,
                                     cd, start, csr_s, dis, disg);
    k_cvt    <<<(NN * 32) / 256, 256, 0, stream>>>(x, dis, xs);
    k_gath_lx<<<NN / 8, 256, 0, stream>>>((const uint2*)xs, csr_s, start, cd,
                                          dis, Lxh);
    k_dmm    <<<782, 256, 0, stream>>>(x, (const f16x8*)Lxh, (const f16x8*)BzT,
                                       (const f16x8*)BhT, (const f16x8*)WgT,
                                       b_xz, b_hz, b_xh, b_hh, disg, hws);
    k_gath_h <<<NN / 8, 256, 0, stream>>>((const uint2*)hws, csr_s, start, cd,
                                          disg, b_gcn, W_lin, b_lin, out);
}

// Round 21
// 113.823 us; speedup vs baseline: 1.1108x; 1.0111x over previous
//
#include <hip/hip_runtime.h>
#include <hip/hip_fp16.h>

#define NN 100000
#define NE 1600000
#define NB 391        // node buckets: node >> 8 (256 nodes/bucket, last=160)
#define NBLK 256      // edge chunks: one block per CU (256x6250 = 1.6M exact)
#define CHUNK 6250
#define EPB 7         // ceil(CHUNK / BT)
#define BT 1024       // k_bucket block size
#define PT 1024       // k_p2 block size
#define ASTR 8192     // arena stride/bucket; counts ~Bin(1.6M,256/1e5):
                      // mean 4096, sd 64 -> 8192 is +64 sd, cannot overflow

// ---- fp16 helpers ----------------------------------------------------------
__device__ __forceinline__ float h16lo(unsigned u) {
    return __half2float(__ushort_as_half((unsigned short)(u & 0xffffu)));
}
__device__ __forceinline__ float h16hi(unsigned u) {
    return __half2float(__ushort_as_half((unsigned short)(u >> 16)));
}
__device__ __forceinline__ unsigned short h16(float f) {
    return __half_as_ushort(__float2half(f));
}
__device__ __forceinline__ unsigned pack2h(float a, float b) {
    return (unsigned)h16(a) | ((unsigned)h16(b) << 16);
}
__device__ __forceinline__ __half2 u2h2(unsigned u) {
    union { unsigned u; __half2 h; } cv; cv.u = u; return cv.h;
}
__device__ __forceinline__ unsigned h2u(__half2 h) {
    union { __half2 h; unsigned u; } cv; cv.h = h; return cv.u;
}

using f16x8  = __attribute__((ext_vector_type(8)))  _Float16;
using f32x16 = __attribute__((ext_vector_type(16))) float;

// ---------------------------------------------------------------------------
// K0: zero the 784 cursor ints AND build the fp16 transposed weight tables.
// ---------------------------------------------------------------------------
__global__ __launch_bounds__(1024) void k_zero(int* __restrict__ p,
                                               const float* __restrict__ W_xz,
                                               const float* __restrict__ W_xh,
                                               const float* __restrict__ W_gcn,
                                               unsigned short* __restrict__ BzT,
                                               unsigned short* __restrict__ BhT,
                                               unsigned short* __restrict__ WgT) {
    int tid = threadIdx.x;
    if (tid < 784) p[tid] = 0;
    for (int idx = tid; idx < 2048; idx += 1024) {
        int f = idx >> 6, k = idx & 63;
        float vz = (k < 32) ? W_xz[k * 32 + f] : W_xz[1024 + (k - 32) * 32 + f];
        float vh = (k < 32) ? W_xh[k * 32 + f] : W_xh[1024 + (k - 32) * 32 + f];
        BzT[idx] = h16(vz);
        BhT[idx] = h16(vh);
    }
    for (int idx = tid; idx < 1024; idx += 1024) {
        int f = idx >> 5, k = idx & 31;
        WgT[idx] = h16(W_gcn[k * 32 + f]);
    }
}

// ---------------------------------------------------------------------------
// B1: fused count + LDS counting-sort + coalesced arena write (R20, passing).
// ---------------------------------------------------------------------------
__global__ __launch_bounds__(BT) void k_bucket(
        const int* __restrict__ src, const int* __restrict__ dst,
        int* __restrict__ cur_d, int* __restrict__ cur_s,
        unsigned* __restrict__ bkd, unsigned char* __restrict__ bks) {
    __shared__ int hd[NB], hs[NB];            // hist, then LDS cursors
    __shared__ int bd[NB], bs[NB];            // claimed global bases
    __shared__ int od[NB], os[NB];            // local exclusive offsets
    __shared__ int t0[512], t1[512];          // scan temps
    __shared__ unsigned       sortd[CHUNK];   // dst-sorted packed entries
    __shared__ unsigned short sbkt [CHUNK];   // bucket id per entry (dst)
    __shared__ unsigned char  sorts[CHUNK];   // src-sorted bytes
    __shared__ unsigned short sbkts[CHUNK];   // bucket id per entry (src)

    int tid = threadIdx.x, blk = blockIdx.x;
    if (tid < NB) { hd[tid] = 0; hs[tid] = 0; }
    __syncthreads();

    int e0 = blk * CHUNK;                     // every block has CHUNK edges
    int sv[EPB], dv[EPB]; bool va[EPB];
#pragma unroll
    for (int u = 0; u < EPB; ++u) {
        int o = u * BT + tid;
        va[u] = o < CHUNK;
        if (va[u]) {
            int e = e0 + o;
            sv[u] = src[e]; dv[u] = dst[e];
            atomicAdd(&hd[dv[u] >> 8], 1);
            atomicAdd(&hs[sv[u] >> 8], 1);
        }
    }
    __syncthreads();

    if (tid < 512) {
        t0[tid] = tid < NB ? hd[tid] : 0;
        t1[tid] = tid < NB ? hs[tid] : 0;
    }
    __syncthreads();
    for (int off = 1; off < 512; off <<= 1) {
        int a = 0, b = 0;
        if (tid < 512 && tid >= off) { a = t0[tid - off]; b = t1[tid - off]; }
        __syncthreads();
        if (tid < 512) { t0[tid] += a; t1[tid] += b; }
        __syncthreads();
    }
    if (tid < NB) {
        int c = hd[tid], c2 = hs[tid];
        od[tid] = t0[tid] - c;
        os[tid] = t1[tid] - c2;
        bd[tid] = c  ? atomicAdd(&cur_d[tid], c)  : 0;
        bs[tid] = c2 ? atomicAdd(&cur_s[tid], c2) : 0;
        hd[tid] = od[tid];            // reuse as LDS cursors
        hs[tid] = os[tid];
    }
    __syncthreads();

#pragma unroll
    for (int u = 0; u < EPB; ++u) if (va[u]) {
        int bu = dv[u] >> 8;
        int p = atomicAdd(&hd[bu], 1);
        sortd[p] = ((unsigned)(dv[u] & 255) << 17) | (unsigned)sv[u];
        sbkt[p]  = (unsigned short)bu;
        int bv = sv[u] >> 8;
        int q = atomicAdd(&hs[bv], 1);
        sorts[q] = (unsigned char)(sv[u] & 255);
        sbkts[q] = (unsigned short)bv;
    }
    __syncthreads();

    for (int i = tid; i < CHUNK; i += BT) {
        int b1 = sbkt[i];
        bkd[b1 * ASTR + bd[b1] + (i - od[b1])] = sortd[i];
        int b2 = sbkts[i];
        bks[b2 * ASTR + bs[b2] + (i - os[b2])] = sorts[i];
    }
}

// ---------------------------------------------------------------------------
// B2 (FUSED scanb+p2d+p2s+norm), 1024 threads (R13/R14/R16, passing).
// ---------------------------------------------------------------------------
__global__ __launch_bounds__(PT) void k_p2(const unsigned* __restrict__ bkd,
                                           const unsigned char* __restrict__ bks,
                                           const int* __restrict__ cur_d,
                                           const int* __restrict__ cur_s,
                                           int* __restrict__ cd,
                                           int* __restrict__ start,
                                           int* __restrict__ csr_s,
                                           float* __restrict__ dis,
                                           float* __restrict__ disg) {
    __shared__ int hist[256], scn[256], hsA[256];
    __shared__ int red[PT];
    int b = blockIdx.x, tid = threadIdx.x;
    if (tid < 256) { hist[tid] = 0; hsA[tid] = 0; }
    int acc = 0;
    for (int i = tid; i < b; i += PT) acc += cur_d[i];
    red[tid] = acc;
    __syncthreads();
    for (int off = PT / 2; off > 0; off >>= 1) {
        if (tid < off) red[tid] += red[tid + off];
        __syncthreads();
    }
    int cb = red[0];

    int eb = b * ASTR, ee = eb + cur_d[b];
    for (int e = eb + tid; e < ee; e += PT)
        atomicAdd(&hist[bkd[e] >> 17], 1);
    int sb = b * ASTR, se = sb + cur_s[b];
    for (int e = sb + tid; e < se; e += PT)
        atomicAdd(&hsA[bks[e]], 1);
    __syncthreads();
    int c = (tid < 256) ? hist[tid] : 0;
    if (tid < 256) scn[tid] = c;
    __syncthreads();
    for (int off = 1; off < 256; off <<= 1) {
        int t = (tid < 256 && tid >= off) ? scn[tid - off] : 0;
        __syncthreads();
        if (tid < 256) scn[tid] += t;
        __syncthreads();
    }
    if (tid < 256) {
        int excl = scn[tid] - c;
        int node = (b << 8) + tid;
        if (node < NN) {
            cd[node] = c;
            start[node] = cb + excl;
            int oc = hsA[tid];
            dis[node]  = oc > 0 ? rsqrtf((float)oc) : 0.0f;
            disg[node] = rsqrtf((float)c + 1.0f);
        }
    }
    __syncthreads();              // all hsA reads done
    if (tid < 256) hsA[tid] = cb + scn[tid] - c;   // reuse as csr cursor
    __syncthreads();
    for (int e = eb + tid; e < ee; e += PT) {
        unsigned pk = bkd[e];
        int p = atomicAdd(&hsA[pk >> 17], 1);
        csr_s[p] = (int)(pk & 0x1FFFFu);
    }
}

// ---------------------------------------------------------------------------
// K_cvt: xs[node][32] = fp16(dis[node]*x[node][:]) — clean copy kernel.
// ---------------------------------------------------------------------------
__global__ __launch_bounds__(256) void k_cvt(const float* __restrict__ x,
                                             const float* __restrict__ dis,
                                             unsigned short* __restrict__ xs) {
    int i = blockIdx.x * 256 + threadIdx.x;
    if (i < NN * 32) xs[i] = h16(x[i] * dis[i >> 5]);
}

// ---------------------------------------------------------------------------
// K_gath_lx: merged gather, FULLY-PACKED fp16 accumulation: no per-batch f32
// flush, butterfly in packed fp16 (2 shfl+hadd2 per acc), unpack once in the
// 8-lane epilogue.  ~35% fewer VALU ops/node than R20.  fp16 partials hold
// up to max-degree (~40) terms: drift ~3e-3 pre-scale, ~1e-3 post-scale.
// ---------------------------------------------------------------------------
__global__ __launch_bounds__(256) void k_gath_lx(const uint2* __restrict__ xs2,
                                                 const int* __restrict__ csr_s,
                                                 const int* __restrict__ start,
                                                 const int* __restrict__ cd,
                                                 const float* __restrict__ dis,
                                                 unsigned* __restrict__ Lxh) {
    int tid = threadIdx.x;
    int node = blockIdx.x * 8 + (tid >> 5);
    int lane = tid & 31, eoff = lane >> 3, c = lane & 7;
    int st = start[node], cn = cd[node];

    __half2 p01 = u2h2(0u), p23 = u2h2(0u);
    int j = 0;
    for (; j + 16 <= cn; j += 16) {        // unmasked packed main loop
        int s0 = csr_s[st + j + eoff];
        int s1 = csr_s[st + j + 4 + eoff];
        int s2 = csr_s[st + j + 8 + eoff];
        int s3 = csr_s[st + j + 12 + eoff];
        uint2 v0 = xs2[s0 * 8 + c];
        uint2 v1 = xs2[s1 * 8 + c];
        uint2 v2 = xs2[s2 * 8 + c];
        uint2 v3 = xs2[s3 * 8 + c];
        p01 = __hadd2(p01, u2h2(v0.x));  p23 = __hadd2(p23, u2h2(v0.y));
        p01 = __hadd2(p01, u2h2(v1.x));  p23 = __hadd2(p23, u2h2(v1.y));
        p01 = __hadd2(p01, u2h2(v2.x));  p23 = __hadd2(p23, u2h2(v2.y));
        p01 = __hadd2(p01, u2h2(v3.x));  p23 = __hadd2(p23, u2h2(v3.y));
    }
    while (j < cn) {                       // masked packed tail (<=2 batches)
        int e0 = j + eoff, e1 = j + 4 + eoff;
        int c0 = e0 < cn ? e0 : cn - 1;  bool m0 = e0 < cn;
        int c1 = e1 < cn ? e1 : cn - 1;  bool m1 = e1 < cn;
        int s0 = csr_s[st + c0], s1 = csr_s[st + c1];
        uint2 v0 = xs2[s0 * 8 + c];
        uint2 v1 = xs2[s1 * 8 + c];
        p01 = __hadd2(p01, u2h2(m0 ? v0.x : 0u));
        p23 = __hadd2(p23, u2h2(m0 ? v0.y : 0u));
        p01 = __hadd2(p01, u2h2(m1 ? v1.x : 0u));
        p23 = __hadd2(p23, u2h2(m1 ? v1.y : 0u));
        j += 8;
    }
    // packed butterfly over the 4 eoff groups (offsets 8, 16)
#pragma unroll
    for (int off = 8; off < 32; off <<= 1) {
        p01 = __hadd2(p01, u2h2((unsigned)__shfl_xor((int)h2u(p01), off, 32)));
        p23 = __hadd2(p23, u2h2((unsigned)__shfl_xor((int)h2u(p23), off, 32)));
    }
    if (lane < 8) {      // c == lane; features 4c..4c+3
        float w = -dis[node];
        unsigned a01 = h2u(p01), a23 = h2u(p23);
        Lxh[node * 16 + 2 * lane]     = pack2h(w * h16lo(a01), w * h16hi(a01));
        Lxh[node * 16 + 2 * lane + 1] = pack2h(w * h16lo(a23), w * h16hi(a23));
    }
}

// ---------------------------------------------------------------------------
// K_dmm: MFMA dense phase (R14/R16/R17, passing).
// ---------------------------------------------------------------------------
__global__ __launch_bounds__(256) void k_dmm(
        const float* __restrict__ x,
        const f16x8* __restrict__ Lxh,    // [node*4 + (c-2)*2 + hi]
        const f16x8* __restrict__ BzT,
        const f16x8* __restrict__ BhT,
        const f16x8* __restrict__ WgT,
        const float* __restrict__ b_xz, const float* __restrict__ b_hz,
        const float* __restrict__ b_xh, const float* __restrict__ b_hh,
        const float* __restrict__ disg,
        unsigned short* __restrict__ hws) {
    __shared__ unsigned short Hl[4 * 1280];   // per-wave 32 x 40 u16 (80B pad)
    int tid = threadIdx.x;
    int wv = blockIdx.x * 4 + (tid >> 6);
    if (wv > 3124) wv = 3124;                 // dup tail wave: same writes, safe
    int l = tid & 63, mrow = l & 31, hi = l >> 5;
    int n0 = wv * 32;
    unsigned short* Hw = Hl + (tid >> 6) * 1280;

    f32x16 accz = {}, acct = {};
    const float* xrow = x + (size_t)(n0 + mrow) * 32;
#pragma unroll
    for (int c = 0; c < 2; ++c) {
        f16x8 a;
        const float* p = xrow + c * 16 + hi * 8;
#pragma unroll
        for (int e = 0; e < 8; ++e) a[e] = (_Float16)p[e];
        accz = __builtin_amdgcn_mfma_f32_32x32x16_f16(a, BzT[mrow * 8 + c * 2 + hi], accz, 0, 0, 0);
        acct = __builtin_amdgcn_mfma_f32_32x32x16_f16(a, BhT[mrow * 8 + c * 2 + hi], acct, 0, 0, 0);
    }
    const f16x8* Lrow = Lxh + (size_t)(n0 + mrow) * 4;
#pragma unroll
    for (int c = 2; c < 4; ++c) {
        f16x8 a = Lrow[(c - 2) * 2 + hi];
        accz = __builtin_amdgcn_mfma_f32_32x32x16_f16(a, BzT[mrow * 8 + c * 2 + hi], accz, 0, 0, 0);
        acct = __builtin_amdgcn_mfma_f32_32x32x16_f16(a, BhT[mrow * 8 + c * 2 + hi], acct, 0, 0, 0);
    }
    float bz = b_xz[mrow] + b_hz[mrow];
    float bh = b_xh[mrow] + b_hh[mrow];
#pragma unroll
    for (int j = 0; j < 16; ++j) {
        float z = accz[j] + bz, t = acct[j] + bh;
        float Z = 1.0f / (1.0f + expf(-z));
        float H = (1.0f - Z) * tanhf(t);
        int r = (j & 3) + 8 * (j >> 2) + 4 * hi;
        Hw[r * 40 + mrow] = h16(H);          // H^T staging (row=node, col=f)
    }
    f32x16 acch = {};
#pragma unroll
    for (int c = 0; c < 2; ++c) {
        f16x8 hfrag = *reinterpret_cast<const f16x8*>(&Hw[mrow * 40 + c * 16 + hi * 8]);
        acch = __builtin_amdgcn_mfma_f32_32x32x16_f16(hfrag, WgT[mrow * 4 + c * 2 + hi], acch, 0, 0, 0);
    }
#pragma unroll
    for (int j = 0; j < 16; ++j) {
        int r = (j & 3) + 8 * (j >> 2) + 4 * hi;
        int node = n0 + r;
        hws[node * 32 + mrow] = h16(disg[node] * acch[j]);
    }
}

// ---------------------------------------------------------------------------
// K_gath_h: merged gather + full fused epilogue; fully-packed fp16 loop.
// ---------------------------------------------------------------------------
__global__ __launch_bounds__(256) void k_gath_h(const uint2* __restrict__ hws2,
                                                const int* __restrict__ csr_s,
                                                const int* __restrict__ start,
                                                const int* __restrict__ cd,
                                                const float* __restrict__ disg,
                                                const float* __restrict__ b_gcn,
                                                const float* __restrict__ W_lin,
                                                const float* __restrict__ b_lin,
                                                float* __restrict__ out) {
    int tid = threadIdx.x;
    int node = blockIdx.x * 8 + (tid >> 5);
    int lane = tid & 31, eoff = lane >> 3, c = lane & 7;
    int st = start[node], cn = cd[node];

    __half2 p01 = u2h2(0u), p23 = u2h2(0u);
    int j = 0;
    for (; j + 16 <= cn; j += 16) {        // unmasked packed main loop
        int s0 = csr_s[st + j + eoff];
        int s1 = csr_s[st + j + 4 + eoff];
        int s2 = csr_s[st + j + 8 + eoff];
        int s3 = csr_s[st + j + 12 + eoff];
        uint2 v0 = hws2[s0 * 8 + c];
        uint2 v1 = hws2[s1 * 8 + c];
        uint2 v2 = hws2[s2 * 8 + c];
        uint2 v3 = hws2[s3 * 8 + c];
        p01 = __hadd2(p01, u2h2(v0.x));  p23 = __hadd2(p23, u2h2(v0.y));
        p01 = __hadd2(p01, u2h2(v1.x));  p23 = __hadd2(p23, u2h2(v1.y));
        p01 = __hadd2(p01, u2h2(v2.x));  p23 = __hadd2(p23, u2h2(v2.y));
        p01 = __hadd2(p01, u2h2(v3.x));  p23 = __hadd2(p23, u2h2(v3.y));
    }
    while (j < cn) {                       // masked packed tail (<=2 batches)
        int e0 = j + eoff, e1 = j + 4 + eoff;
        int c0 = e0 < cn ? e0 : cn - 1;  bool m0 = e0 < cn;
        int c1 = e1 < cn ? e1 : cn - 1;  bool m1 = e1 < cn;
        int s0 = csr_s[st + c0], s1 = csr_s[st + c1];
        uint2 v0 = hws2[s0 * 8 + c];
        uint2 v1 = hws2[s1 * 8 + c];
        p01 = __hadd2(p01, u2h2(m0 ? v0.x : 0u));
        p23 = __hadd2(p23, u2h2(m0 ? v0.y : 0u));
        p01 = __hadd2(p01, u2h2(m1 ? v1.x : 0u));
        p23 = __hadd2(p23, u2h2(m1 ? v1.y : 0u));
        j += 8;
    }
#pragma unroll
    for (int off = 8; off < 32; off <<= 1) {
        p01 = __hadd2(p01, u2h2((unsigned)__shfl_xor((int)h2u(p01), off, 32)));
        p23 = __hadd2(p23, u2h2((unsigned)__shfl_xor((int)h2u(p23), off, 32)));
    }
    float p = 0.0f;
    if (lane < 8) {      // c == lane; features f0 = 4c
        unsigned a01 = h2u(p01), a23 = h2u(p23);
        uint2 sv = hws2[node * 8 + lane];   // self row (pre-scaled by disg)
        float dg = disg[node];
        int f0 = 4 * lane;
        float h0 = dg * (h16lo(a01) + h16lo(sv.x)) + b_gcn[f0];
        float h1 = dg * (h16hi(a01) + h16hi(sv.x)) + b_gcn[f0 + 1];
        float h2 = dg * (h16lo(a23) + h16lo(sv.y)) + b_gcn[f0 + 2];
        float h3 = dg * (h16hi(a23) + h16hi(sv.y)) + b_gcn[f0 + 3];
        p = fmaxf(h0, 0.0f) * W_lin[f0]
          + fmaxf(h1, 0.0f) * W_lin[f0 + 1]
          + fmaxf(h2, 0.0f) * W_lin[f0 + 2]
          + fmaxf(h3, 0.0f) * W_lin[f0 + 3];
    }
    p += __shfl_xor(p, 1, 32);
    p += __shfl_xor(p, 2, 32);
    p += __shfl_xor(p, 4, 32);
    if (lane == 0) out[node] = p + b_lin[0];
}

extern "C" void kernel_launch(void* const* d_in, const int* in_sizes, int n_in,
                              void* d_out, int out_size, void* d_ws, size_t ws_size,
                              hipStream_t stream) {
    const float* x     = (const float*)d_in[0];
    const int*   ei    = (const int*)d_in[1];
    const int*   src   = ei;
    const int*   dst   = ei + NE;
    const float* W_xz  = (const float*)d_in[2];
    const float* b_xz  = (const float*)d_in[3];
    const float* b_hz  = (const float*)d_in[5];
    // W_xr/b_xr/W_hr/b_hr (d_in[6..9]) are dead: R only multiplies H0 == 0.
    const float* W_xh  = (const float*)d_in[10];
    const float* b_xh  = (const float*)d_in[11];
    const float* b_hh  = (const float*)d_in[13];
    const float* W_gcn = (const float*)d_in[14];
    const float* b_gcn = (const float*)d_in[15];
    const float* W_lin = (const float*)d_in[16];
    const float* b_lin = (const float*)d_in[17];
    float* out = (float*)d_out;

    // Workspace (4B words), ~36.8 MB (R19/R20 layout).
    // cur_d/cur_s zeroed by k_zero (which also builds weight tables).
    // Aliases: xs (16N words) overlays bkd arena (dead after k_p2).
    int* w = (int*)d_ws;
    int* cur_d = w;                       w += 392;
    int* cur_s = w;                       w += 392;
    int* cd    = w;                       w += NN;
    int* start = w;                       w += NN;
    float* dis  = (float*)w;              w += NN;
    float* disg = (float*)w;              w += NN;
    unsigned short* hws = (unsigned short*)w;  w += 16 * NN;    // 32 fp16/node
    unsigned* Lxh = (unsigned*)w;         w += 16 * NN;         // 32 fp16/node
    unsigned* bkd = (unsigned*)w;         w += NB * ASTR;       // 3,203,072
    unsigned char* bks = (unsigned char*)w; w += (NB * ASTR) / 4;
    int* csr_s = w;                       w += NE;
    unsigned short* BzT = (unsigned short*)w; w += 1024;        // 32f x 64k
    unsigned short* BhT = (unsigned short*)w; w += 1024;
    unsigned short* WgT = (unsigned short*)w; w += 512;         // 32f x 32k
    unsigned short* xs = (unsigned short*)bkd;                  // alias

    k_zero   <<<1, 1024, 0, stream>>>(cur_d, W_xz, W_xh, W_gcn, BzT, BhT, WgT);
    k_bucket <<<NBLK, BT, 0, stream>>>(src, dst, cur_d, cur_s, bkd, bks);
    k_p2     <<<NB, PT, 0, stream>>>(bkd, bks, cur_d, cur_s,
                                     cd, start, csr_s, dis, disg);
    k_cvt    <<<(NN * 32) / 256, 256, 0, stream>>>(x, dis, xs);
    k_gath_lx<<<NN / 8, 256, 0, stream>>>((const uint2*)xs, csr_s, start, cd,
                                          dis, Lxh);
    k_dmm    <<<782, 256, 0, stream>>>(x, (const f16x8*)Lxh, (const f16x8*)BzT,
                                       (const f16x8*)BhT, (const f16x8*)WgT,
                                       b_xz, b_hz, b_xh, b_hh, disg, hws);
    k_gath_h <<<NN / 8, 256, 0, stream>>>((const uint2*)hws, csr_s, start, cd,
                                          disg, b_gcn, W_lin, b_lin, out);
}